// Round 1
// 834.618 us; speedup vs baseline: 1.2715x; 1.2715x over previous
//
#include <hip/hip_runtime.h>

#define NN 10000
#define EE 160000
#define DD 512
#define EDIM 128
#define LLAYERS 3
#define LN_EPS 1e-5f

typedef __attribute__((ext_vector_type(8))) short bf16x8;
typedef __attribute__((ext_vector_type(4))) float f32x4;

__device__ __forceinline__ unsigned short f2b(float f) {
    union { float f; unsigned u; } v; v.f = f;
    unsigned r = (v.u + 0x7fffu + ((v.u >> 16) & 1u)) >> 16;
    return (unsigned short)r;
}
__device__ __forceinline__ float b2f(unsigned short s) {
    union { unsigned u; float f; } v; v.u = ((unsigned)s) << 16;
    return v.f;
}
__device__ __forceinline__ unsigned short f2h(float f) {
    _Float16 h = (_Float16)f;
    unsigned short u; __builtin_memcpy(&u, &h, 2);
    return u;
}
__device__ __forceinline__ float h2f(unsigned short u) {
    _Float16 h; __builtin_memcpy(&h, &u, 2);
    return (float)h;
}

// ---------------- CSR build: counting sort of edges by dst ----------------
__global__ __launch_bounds__(256) void hist_kernel(
    const int* __restrict__ dstv, int* __restrict__ deg)
{
    int e = blockIdx.x * 256 + threadIdx.x;
    if (e < EE) atomicAdd(&deg[dstv[e]], 1);
}

__global__ __launch_bounds__(256) void scan_kernel(
    const int* __restrict__ deg, int* __restrict__ base, int* __restrict__ cursor)
{
    __shared__ int sums[256];
    const int t = threadIdx.x;
    const int CH = 40;                       // 256*40 = 10240 >= NN
    int lo = t * CH;
    int hi = lo + CH; if (hi > NN) hi = NN;
    int s = 0;
    for (int i = lo; i < hi; i++) s += deg[i];
    sums[t] = s;
    __syncthreads();
    for (int off = 1; off < 256; off <<= 1) {
        int v = (t >= off) ? sums[t - off] : 0;
        __syncthreads();
        sums[t] += v;
        __syncthreads();
    }
    int run = (t == 0) ? 0 : sums[t - 1];
    for (int i = lo; i < hi; i++) {
        base[i] = run; cursor[i] = run;
        run += deg[i];
    }
}

__global__ __launch_bounds__(256) void scatter_kernel(
    const int* __restrict__ srcv, const int* __restrict__ dstv,
    int* __restrict__ cursor,
    int* __restrict__ ssrc, int* __restrict__ sdst, int* __restrict__ perm)
{
    int e = blockIdx.x * 256 + threadIdx.x;
    if (e < EE) {
        int d = dstv[e];
        int pos = atomicAdd(&cursor[d], 1);
        ssrc[pos] = srcv[e];
        sdst[pos] = d;
        perm[pos] = e;
    }
}

// ---------------- fp32 -> bf16 transpose (src[K][N] -> dst[N][K]) ----------------
__global__ __launch_bounds__(256) void transpose_bf16_kernel(
    const float* __restrict__ src, unsigned short* __restrict__ dst, int K, int N)
{
    __shared__ float t[32][33];
    const int x = threadIdx.x & 31;
    const int y = threadIdx.x >> 5;          // 0..7
    const int bn = blockIdx.x * 32;
    const int bk = blockIdx.y * 32;
    #pragma unroll
    for (int j = 0; j < 32; j += 8)
        t[y + j][x] = src[(size_t)(bk + y + j) * N + bn + x];
    __syncthreads();
    #pragma unroll
    for (int j = 0; j < 32; j += 8)
        dst[(size_t)(bn + y + j) * K + bk + x] = f2b(t[x][y + j]);
}

// ---------------- fp32 -> bf16 elementwise convert (4 elems/thread) ----------------
__global__ __launch_bounds__(256) void cvt_bf16_kernel(
    const float* __restrict__ src, unsigned short* __restrict__ dst)
{
    int i = blockIdx.x * 256 + threadIdx.x;
    float4 v = ((const float4*)src)[i];
    uint2 o;
    o.x = (unsigned)f2b(v.x) | ((unsigned)f2b(v.y) << 16);
    o.y = (unsigned)f2b(v.z) | ((unsigned)f2b(v.w) << 16);
    ((uint2*)dst)[i] = o;
}

// ---------------- perm-gather edge_attr fp32 -> bf16, sorted order ----------------
// thread handles 4 cols of one sorted row. grid = cnt*32/256 = cnt/8 (cnt % 128 == 0).
__global__ __launch_bounds__(256) void gather_cvt_kernel(
    const float* __restrict__ ea, const int* __restrict__ perm,
    unsigned short* __restrict__ out, int elo)
{
    int i = blockIdx.x * 256 + threadIdx.x;
    int r = i >> 5, c4 = (i & 31) * 4;
    const float* p = ea + (size_t)perm[elo + r] * EDIM + c4;
    float4 v = *(const float4*)p;
    uint2 o;
    o.x = (unsigned)f2b(v.x) | ((unsigned)f2b(v.y) << 16);
    o.y = (unsigned)f2b(v.z) | ((unsigned)f2b(v.w) << 16);
    *(uint2*)&out[(size_t)r * EDIM + c4] = o;
}

// ---------------- msg GEMM: msg[cnt][512] fp16 = Abf[cnt][128] @ WeT^T + be ----------
// Block: 128 edges x 128 cols, K = 128 in one shot. 4 waves: wave w -> row-half
// (w&1)*64, col-half (w>>1)*64. A staged in LDS (coalesced, already bf16);
// B read from global (WeT layer slice = 128 KB, L2-resident).
// grid = (4 slabs, cnt/128) — slab fastest so 4 blocks sharing an A-tile are
// temporally adjacent (L3 dedups the A fetch).
#define MEP 136    // A pitch: 128+8 shorts -> 2-way bank alias (free)
__global__ __launch_bounds__(256) void msg_gemm(
    const unsigned short* __restrict__ Abf,   // [cnt][128] bf16 (chunk-local)
    const unsigned short* __restrict__ WeT,   // [512 n][128 k] bf16 (layer slice)
    const float* __restrict__ be,             // [512]
    unsigned short* __restrict__ msg)         // [cnt][512] fp16 (chunk-local)
{
    __shared__ unsigned short sA[128 * MEP];  // 34.8 KB

    const int tid  = threadIdx.x;
    const int c0   = blockIdx.x * 128;        // col slab
    const int e0   = blockIdx.y * 128;        // edge tile (chunk-local)
    const int w    = tid >> 6;
    const int lane = tid & 63;
    const int quad = lane >> 4;
    const int l16  = lane & 15;
    const int mh   = (w & 1) * 64;
    const int nsl  = (w >> 1) * 64;

    // stage A: 128 rows x 16 segs of 8 bf16 (fully coalesced)
    for (int i = tid; i < 128 * 16; i += 256) {
        int r = i >> 4, seg = i & 15;
        *(uint4*)&sA[r * MEP + seg * 8] =
            *(const uint4*)&Abf[(size_t)(e0 + r) * EDIM + seg * 8];
    }
    __syncthreads();

    f32x4 acc[4][4];
    #pragma unroll
    for (int mr = 0; mr < 4; mr++)
        #pragma unroll
        for (int nb = 0; nb < 4; nb++)
            acc[mr][nb] = (f32x4){0.f, 0.f, 0.f, 0.f};

    #pragma unroll
    for (int ks = 0; ks < 4; ks++) {
        const int ko = ks * 32 + quad * 8;
        bf16x8 a[4];
        #pragma unroll
        for (int mr = 0; mr < 4; mr++)
            a[mr] = *(const bf16x8*)&sA[(mh + mr * 16 + l16) * MEP + ko];
        bf16x8 b[4];
        #pragma unroll
        for (int nb = 0; nb < 4; nb++)
            b[nb] = *(const bf16x8*)&WeT[(size_t)(c0 + nsl + nb * 16 + l16) * EDIM + ko];
        #pragma unroll
        for (int mr = 0; mr < 4; mr++)
            #pragma unroll
            for (int nb = 0; nb < 4; nb++)
                acc[mr][nb] = __builtin_amdgcn_mfma_f32_16x16x32_bf16(a[mr], b[nb], acc[mr][nb], 0, 0, 0);
    }

    #pragma unroll
    for (int mr = 0; mr < 4; mr++) {
        const int rb = e0 + mh + mr * 16 + quad * 4;
        #pragma unroll
        for (int nb = 0; nb < 4; nb++) {
            const int c = c0 + nsl + nb * 16 + l16;
            const float bv = be[c];
            const f32x4 v = acc[mr][nb];
            #pragma unroll
            for (int reg = 0; reg < 4; reg++)
                msg[(size_t)(rb + reg) * DD + c] = f2h(v[reg] + bv);
        }
    }
}

// ---------------- CSR per-dst aggregation: zero atomics, zero LDS -----------------
// One block per dst row; thread t owns cols (2t, 2t+1). For each in-edge p:
// acc += relu(fp16 msg[p] + bf16 h[src[p]]). Last chunk emits
// aprime = bf16((1+eps)*h + acc); earlier chunks spill fp32 partials to aggp.
__global__ __launch_bounds__(256) void agg_kernel(
    const unsigned short* __restrict__ h_bf,
    const unsigned short* __restrict__ msg,   // fp16 bits, chunk-local rows
    const int* __restrict__ ssrc,
    const int* __restrict__ basep,
    const int* __restrict__ degp,
    const float* __restrict__ epsp,
    float* __restrict__ aggp,
    unsigned short* __restrict__ aprime,
    int elo, int ehi, int first, int last)
{
    const int d  = blockIdx.x;
    const int b0 = basep[d];
    const int b1 = b0 + degp[d];
    int lo = b0 > elo ? b0 : elo;
    int hi = b1 < ehi ? b1 : ehi;
    if (!first && !last && lo >= hi) return;   // middle chunk, nothing to add

    const int t  = threadIdx.x;
    const int c2 = t * 2;

    float a0 = 0.f, a1 = 0.f;
    if (!first) {
        float2 pv = *(const float2*)&aggp[(size_t)d * DD + c2];
        a0 = pv.x; a1 = pv.y;
    }
    for (int p = lo; p < hi; p++) {
        const int s = ssrc[p];
        unsigned mv = *(const unsigned*)&msg[(size_t)(p - elo) * DD + c2];
        unsigned hv = *(const unsigned*)&h_bf[(size_t)s * DD + c2];
        a0 += fmaxf(h2f((unsigned short)(mv & 0xffffu)) + b2f((unsigned short)(hv & 0xffffu)), 0.f);
        a1 += fmaxf(h2f((unsigned short)(mv >> 16))     + b2f((unsigned short)(hv >> 16)),     0.f);
    }
    if (last) {
        const float es = 1.0f + epsp[0];
        unsigned hv = *(const unsigned*)&h_bf[(size_t)d * DD + c2];
        unsigned o = (unsigned)f2b(es * b2f((unsigned short)(hv & 0xffffu)) + a0)
                   | ((unsigned)f2b(es * b2f((unsigned short)(hv >> 16))    + a1) << 16);
        *(unsigned*)&aprime[(size_t)d * DD + c2] = o;
    } else {
        *(float2*)&aggp[(size_t)d * DD + c2] = make_float2(a0, a1);
    }
}

// ---------------- node GEMM (MFMA bf16) ----------------
// C[M,512] = act(A[M,512] @ W[512,512] + bias); W given as WT[n][k] bf16.
#define GPITCH 136
template <bool RELU, bool OUTBF>
__global__ __launch_bounds__(256) void mfma_gemm(
    const unsigned short* __restrict__ A,    // [M][512] bf16
    const unsigned short* __restrict__ WT,   // [512 n][512 k] bf16
    const float* __restrict__ bias,          // [512] fp32
    void* __restrict__ Cout, int M)
{
    __shared__ unsigned short sA[64 * GPITCH];    // 17.4 KB
    __shared__ unsigned short sB[128 * GPITCH];   // 34.8 KB

    const int tid  = threadIdx.x;
    const int m0   = blockIdx.x * 64;
    const int c0   = blockIdx.y * 128;
    const int w    = tid >> 6;
    const int lane = tid & 63;
    const int quad = lane >> 4;
    const int l16  = lane & 15;
    const int mh   = (w & 1) * 32;
    const int nsl  = (w >> 1) * 64;

    f32x4 acc[2][4];
    #pragma unroll
    for (int mr = 0; mr < 2; mr++)
        #pragma unroll
        for (int nb = 0; nb < 4; nb++)
            acc[mr][nb] = (f32x4){0.f, 0.f, 0.f, 0.f};

    for (int kc = 0; kc < DD; kc += 128) {
        __syncthreads();
        for (int i = tid; i < 64 * 16; i += 256) {   // A: 64 rows x 16 segs
            int r = i >> 4, seg = i & 15;
            int gm = m0 + r;
            uint4 v = make_uint4(0u, 0u, 0u, 0u);
            if (gm < M)
                v = *(const uint4*)&A[(size_t)gm * DD + kc + seg * 8];
            *(uint4*)&sA[r * GPITCH + seg * 8] = v;
        }
        for (int i = tid; i < 128 * 16; i += 256) {  // B: 128 rows x 16 segs
            int r = i >> 4, seg = i & 15;
            *(uint4*)&sB[r * GPITCH + seg * 8] =
                *(const uint4*)&WT[(size_t)(c0 + r) * DD + kc + seg * 8];
        }
        __syncthreads();
        #pragma unroll
        for (int ks = 0; ks < 4; ks++) {
            const int ko = ks * 32 + quad * 8;
            bf16x8 a0 = *(const bf16x8*)&sA[(mh + l16) * GPITCH + ko];
            bf16x8 a1 = *(const bf16x8*)&sA[(mh + 16 + l16) * GPITCH + ko];
            bf16x8 b[4];
            #pragma unroll
            for (int nb = 0; nb < 4; nb++)
                b[nb] = *(const bf16x8*)&sB[(nsl + nb * 16 + l16) * GPITCH + ko];
            #pragma unroll
            for (int nb = 0; nb < 4; nb++) {
                acc[0][nb] = __builtin_amdgcn_mfma_f32_16x16x32_bf16(a0, b[nb], acc[0][nb], 0, 0, 0);
                acc[1][nb] = __builtin_amdgcn_mfma_f32_16x16x32_bf16(a1, b[nb], acc[1][nb], 0, 0, 0);
            }
        }
    }

    #pragma unroll
    for (int mr = 0; mr < 2; mr++) {
        const int rbase = m0 + mh + mr * 16 + quad * 4;
        #pragma unroll
        for (int nb = 0; nb < 4; nb++) {
            const int c = c0 + nsl + nb * 16 + l16;
            const float bv = bias[c];
            const f32x4 v = acc[mr][nb];
            #pragma unroll
            for (int reg = 0; reg < 4; reg++) {
                int gm = rbase + reg;
                if (gm < M) {
                    float val = v[reg] + bv;
                    if (RELU) val = fmaxf(val, 0.f);
                    if (OUTBF) ((unsigned short*)Cout)[(size_t)gm * DD + c] = f2b(val);
                    else       ((float*)Cout)[(size_t)gm * DD + c] = val;
                }
            }
        }
    }
}

// ---------------- fused ReLU + LayerNorm (bf16 in/out, fp32 stats) ----------------
__global__ __launch_bounds__(256) void relu_ln_kernel(
    const unsigned short* __restrict__ g2,
    const float* __restrict__ gamma,
    const float* __restrict__ beta,
    unsigned short* __restrict__ hout)
{
    __shared__ float ss[4], ssq[4];
    const int row = blockIdx.x;
    const int tid = threadIdx.x;
    const unsigned short* gr = g2 + (size_t)row * DD;

    float v0 = fmaxf(b2f(gr[tid]), 0.f);
    float v1 = fmaxf(b2f(gr[tid + 256]), 0.f);
    float s  = v0 + v1;
    float sq = v0 * v0 + v1 * v1;
    #pragma unroll
    for (int off = 32; off > 0; off >>= 1) {
        s  += __shfl_down(s, off);
        sq += __shfl_down(sq, off);
    }
    const int wave = tid >> 6;
    const int lane = tid & 63;
    if (lane == 0) { ss[wave] = s; ssq[wave] = sq; }
    __syncthreads();
    if (tid == 0) {
        float S  = ss[0] + ss[1] + ss[2] + ss[3];
        float SQ = ssq[0] + ssq[1] + ssq[2] + ssq[3];
        float mu = S * (1.f / 512.f);
        float var = SQ * (1.f / 512.f) - mu * mu;
        ss[0]  = mu;
        ssq[0] = rsqrtf(var + LN_EPS);
    }
    __syncthreads();
    float mu = ss[0], rstd = ssq[0];
    hout[(size_t)row * DD + tid] =
        f2b((v0 - mu) * rstd * gamma[tid] + beta[tid]);
    hout[(size_t)row * DD + tid + 256] =
        f2b((v1 - mu) * rstd * gamma[tid + 256] + beta[tid + 256]);
}

extern "C" void kernel_launch(void* const* d_in, const int* in_sizes, int n_in,
                              void* d_out, int out_size, void* d_ws, size_t ws_size,
                              hipStream_t stream)
{
    (void)in_sizes; (void)n_in; (void)out_size;

    const float* x          = (const float*)d_in[0];
    const int*   edge_index = (const int*)d_in[1];   // int32 per harness contract
    const float* edge_attr  = (const float*)d_in[2];
    const float* We         = (const float*)d_in[3];
    const float* be         = (const float*)d_in[4];
    const float* eps        = (const float*)d_in[5];
    const float* W1         = (const float*)d_in[6];
    const float* b1         = (const float*)d_in[7];
    const float* W2         = (const float*)d_in[8];
    const float* b2         = (const float*)d_in[9];
    const float* gamma      = (const float*)d_in[10];
    const float* beta       = (const float*)d_in[11];
    const float* Wf         = (const float*)d_in[12];
    const float* bf         = (const float*)d_in[13];

    // ---- workspace layout ----
    unsigned short* h_bf   = (unsigned short*)d_ws;                 // [N*512] bf16
    unsigned short* aprime = h_bf + (size_t)NN * DD;                // [N*512] bf16
    unsigned short* t1     = aprime + (size_t)NN * DD;              // [N*512] bf16
    unsigned short* t2     = t1 + (size_t)NN * DD;                  // [N*512] bf16
    unsigned short* WeT    = t2 + (size_t)NN * DD;                  // [3][512][128]
    unsigned short* W1T    = WeT + (size_t)LLAYERS * DD * EDIM;     // [3][512][512]
    unsigned short* W2T    = W1T + (size_t)LLAYERS * DD * DD;
    unsigned short* WfT    = W2T + (size_t)LLAYERS * DD * DD;       // [512][512]
    int* deg    = (int*)(WfT + (size_t)DD * DD);
    int* basep  = deg + NN;
    int* cursor = basep + NN;
    int* ssrc   = cursor + NN;
    int* sdst   = ssrc + EE;
    int* perm   = sdst + EE;
    float* aggp = (float*)(perm + EE);                              // [N*512] fp32 partials
    unsigned short* ea_hf = (unsigned short*)(aggp + (size_t)NN * DD);

    // dynamic msg/ea capacity from remaining workspace
    size_t used = (size_t)((unsigned char*)ea_hf - (unsigned char*)d_ws);
    size_t rem  = ws_size > used ? ws_size - used : 0;
    const size_t EA_FULL  = (size_t)EE * EDIM * 2;   // 41.0 MB
    const size_t MSG_FULL = (size_t)EE * DD * 2;     // 163.8 MB
    int ea_full; long long capE;
    if (rem >= EA_FULL + MSG_FULL) {
        ea_full = 1; capE = EE;                      // single chunk (expected path)
    } else if (rem >= EA_FULL + (size_t)32 * 1024 * 1024) {
        ea_full = 1;
        capE = (long long)((rem - EA_FULL) / ((size_t)DD * 2)) & ~127LL;
    } else {
        ea_full = 0;
        capE = (long long)(rem / ((size_t)(EDIM + DD) * 2)) & ~127LL;
        if (capE < 128) capE = 128;
    }
    if (capE > EE) capE = EE;
    unsigned short* msg = ea_hf + (ea_full ? (size_t)EE * EDIM : (size_t)capE * EDIM);

    const int* srcv = edge_index;
    const int* dstv = edge_index + EE;

    // ---- prepass: sort, converts, transposes ----
    hipMemsetAsync(deg, 0, NN * sizeof(int), stream);
    hist_kernel<<<dim3((EE + 255) / 256), 256, 0, stream>>>(dstv, deg);
    scan_kernel<<<dim3(1), 256, 0, stream>>>(deg, basep, cursor);
    scatter_kernel<<<dim3((EE + 255) / 256), 256, 0, stream>>>(
        srcv, dstv, cursor, ssrc, sdst, perm);

    cvt_bf16_kernel<<<dim3(NN * DD / 4 / 256), 256, 0, stream>>>(x, h_bf);
    for (int l = 0; l < LLAYERS; l++) {
        transpose_bf16_kernel<<<dim3(DD / 32, EDIM / 32), 256, 0, stream>>>(
            We + (size_t)l * EDIM * DD, WeT + (size_t)l * DD * EDIM, EDIM, DD);
        transpose_bf16_kernel<<<dim3(DD / 32, DD / 32), 256, 0, stream>>>(
            W1 + (size_t)l * DD * DD, W1T + (size_t)l * DD * DD, DD, DD);
        transpose_bf16_kernel<<<dim3(DD / 32, DD / 32), 256, 0, stream>>>(
            W2 + (size_t)l * DD * DD, W2T + (size_t)l * DD * DD, DD, DD);
    }
    transpose_bf16_kernel<<<dim3(DD / 32, DD / 32), 256, 0, stream>>>(Wf, WfT, DD, DD);

    if (ea_full)
        gather_cvt_kernel<<<dim3(EE / 8), 256, 0, stream>>>(edge_attr, perm, ea_hf, 0);

    dim3 ggrid((NN + 63) / 64, DD / 128);

    const int nch = (int)((EE + capE - 1) / capE);
    for (int l = 0; l < LLAYERS; l++) {
        for (int c = 0; c < nch; c++) {
            const int elo = (int)((long long)c * capE);
            const int cnt = (EE - elo < capE) ? (EE - elo) : (int)capE;
            if (!ea_full)
                gather_cvt_kernel<<<dim3(cnt / 8), 256, 0, stream>>>(edge_attr, perm, ea_hf, elo);
            const unsigned short* Ab = ea_full ? ea_hf + (size_t)elo * EDIM : ea_hf;
            msg_gemm<<<dim3(4, cnt / 128), 256, 0, stream>>>(
                Ab, WeT + (size_t)l * DD * EDIM, be + (size_t)l * DD, msg);
            agg_kernel<<<dim3(NN), 256, 0, stream>>>(
                h_bf, msg, ssrc, basep, deg, eps + l, aggp, aprime,
                elo, elo + cnt, c == 0 ? 1 : 0, c == nch - 1 ? 1 : 0);
        }
        // gemm1: relu(aprime @ W1 + b1) -> t1 (bf16)
        mfma_gemm<true, true><<<ggrid, 256, 0, stream>>>(
            aprime, W1T + (size_t)l * DD * DD, b1 + (size_t)l * DD, t1, NN);
        // gemm2: t1 @ W2 + b2 -> t2 (bf16)
        mfma_gemm<false, true><<<ggrid, 256, 0, stream>>>(
            t1, W2T + (size_t)l * DD * DD, b2 + (size_t)l * DD, t2, NN);
        relu_ln_kernel<<<dim3(NN), 256, 0, stream>>>(
            t2, gamma + (size_t)l * DD, beta + (size_t)l * DD, h_bf);
    }
    mfma_gemm<false, false><<<ggrid, 256, 0, stream>>>(h_bf, WfT, bf, d_out, NN);
}